// Round 7
// baseline (246.862 us; speedup 1.0000x reference)
//
#include <hip/hip_runtime.h>
#include <cstdint>
#include <cstddef>

// B=2, T=4096, C=1024, H=4, G=1, hd=256, window=512, rope base 1e6, eps 1e-6.
#define T_SEQ 4096
#define NB    2
#define CDIM  1024
#define HD    256
#define NH    4

typedef __attribute__((ext_vector_type(8))) __bf16 bf16x8;
typedef __attribute__((ext_vector_type(4))) __bf16 bf16x4;
typedef __attribute__((ext_vector_type(4))) float  floatx4;

__device__ __forceinline__ floatx4 mfma16(bf16x8 a, bf16x8 b, floatx4 c) {
  return __builtin_amdgcn_mfma_f32_16x16x32_bf16(a, b, c, 0, 0, 0);
}

// async global->LDS, 16B/lane. LDS dest is wave-uniform base + lane*16 (no
// scatter) -- bank-deconflict swizzles are applied to the GLOBAL source
// address (XOR of the 16B-chunk index, stays inside one row's span).
__device__ __forceinline__ void gl2lds16(const void* g, void* l) {
  __builtin_amdgcn_global_load_lds(
      (__attribute__((address_space(1))) void*)g,
      (__attribute__((address_space(3))) void*)l, 16, 0, 0);
}

// ------------------------------------------- fp32 -> bf16, all 5 inputs fused
__global__ __launch_bounds__(256) void cvt_all(const float* __restrict__ x,
                                               const float* __restrict__ wq,
                                               const float* __restrict__ wk,
                                               const float* __restrict__ wv,
                                               const float* __restrict__ wo,
                                               __bf16* __restrict__ xb,
                                               __bf16* __restrict__ wb,
                                               __bf16* __restrict__ wob) {
  int i = blockIdx.x * 256 + threadIdx.x;   // float4 index, [0, 2752512)
  const float* src;
  __bf16* dst;
  int off;
  if (i < 2097152)      { src = x;  dst = xb;            off = i; }
  else if (i < 2359296) { src = wq; dst = wb;            off = i - 2097152; }
  else if (i < 2424832) { src = wk; dst = wb + 1048576;  off = i - 2359296; }
  else if (i < 2490368) { src = wv; dst = wb + 1310720;  off = i - 2424832; }
  else                  { src = wo; dst = wob;           off = i - 2490368; }
  float4 v = ((const float4*)src)[off];
  bf16x4 o;
  o[0] = (__bf16)v.x; o[1] = (__bf16)v.y; o[2] = (__bf16)v.z; o[3] = (__bf16)v.w;
  *(bf16x4*)&dst[(size_t)off * 4] = o;
}

// ------------------------------------------------- C(M,N) = A(M,K) @ B(N,K)^T
// A-fragments read DIRECT from global (L2-served; halves LDS traffic, the
// binding pipe). B staged via global_load_lds, double-buffered, ONE barrier
// per K-iter, staged one full compute phase ahead. LDS 32 KB -> 3 blocks/CU.
// M,N multiples of 128; K multiple of 64.
template <typename OutT>
__global__ __launch_bounds__(256, 3) void gemm_bt(const __bf16* __restrict__ A,
                                                  const __bf16* __restrict__ B,
                                                  OutT* __restrict__ C,
                                                  int M, int N, int K) {
  __shared__ __bf16 Bs[2][128 * 64];   // 2 x 16 KB
  const int tid  = threadIdx.x;
  const int lane = tid & 63;
  const int wave = tid >> 6;
  const int wm = wave >> 1, wn = wave & 1;
  const int lrow = lane & 15, quad = lane >> 4;
  const int l7 = lrow & 7;
  const int bm = blockIdx.y, bn = blockIdx.x;

  const __bf16* gA = A + (size_t)(bm * 128) * K;
  const __bf16* gB = B + (size_t)(bn * 128) * K;
  const int arow = tid >> 3;
  const int acol = ((tid & 7) ^ ((tid >> 3) & 7)) * 8;

  floatx4 acc[4][4] = {};
  const int nkt = K >> 6;

  // prologue: stage B(0)
#pragma unroll
  for (int i = 0; i < 4; ++i)
    gl2lds16(gB + (size_t)(i * 32 + arow) * K + acol, &Bs[0][i * 2048 + tid * 8]);

  for (int kt = 0; kt < nkt; ++kt) {
    __syncthreads();   // B(kt) staged & visible; B(kt-1) reads all done

    if (kt + 1 < nkt) {   // stage B(kt+1); consumed after the NEXT barrier
      const __bf16* src = gB + (kt + 1) * 64;
#pragma unroll
      for (int i = 0; i < 4; ++i)
        gl2lds16(src + (size_t)(i * 32 + arow) * K + acol,
                 &Bs[(kt + 1) & 1][i * 2048 + tid * 8]);
    }

    // A fragments direct from global (16 rows x 64B per instr; L2-resident)
    const __bf16* Ab = gA + kt * 64;
    bf16x8 af[2][4];
#pragma unroll
    for (int kk = 0; kk < 2; ++kk)
#pragma unroll
      for (int mi = 0; mi < 4; ++mi)
        af[kk][mi] = *(const bf16x8*)&Ab[(size_t)(wm * 64 + mi * 16 + lrow) * K +
                                         kk * 32 + quad * 8];

    const __bf16* Bb = Bs[kt & 1];
#pragma unroll
    for (int kk = 0; kk < 2; ++kk) {
      bf16x8 bfr[4];
#pragma unroll
      for (int ni = 0; ni < 4; ++ni)
        bfr[ni] = *(const bf16x8*)&Bb[(wn * 64 + ni * 16 + lrow) * 64 +
                                      ((kk * 4 + quad) ^ l7) * 8];
#pragma unroll
      for (int mi = 0; mi < 4; ++mi)
#pragma unroll
        for (int ni = 0; ni < 4; ++ni)
          acc[mi][ni] = mfma16(af[kk][mi], bfr[ni], acc[mi][ni]);
    }
  }

  const int row0 = bm * 128 + wm * 64;
  const int col0 = bn * 128 + wn * 64;
#pragma unroll
  for (int mi = 0; mi < 4; ++mi)
#pragma unroll
    for (int ni = 0; ni < 4; ++ni)
#pragma unroll
      for (int r = 0; r < 4; ++r) {
        int row = row0 + mi * 16 + quad * 4 + r;   // C/D: row = quad*4 + reg
        int col = col0 + ni * 16 + lrow;           //      col = lane&15
        C[(size_t)row * N + col] = (OutT)acc[mi][ni][r];
      }
}

// ------------------------------------------------ RMSNorm + RoPE (+ V transpose)
__global__ __launch_bounds__(256) void rmsrope(const __bf16* __restrict__ qkv,
                                               const float* __restrict__ qg,
                                               const float* __restrict__ kg,
                                               __bf16* __restrict__ qr,
                                               __bf16* __restrict__ kr,
                                               __bf16* __restrict__ vt) {
  __shared__ __bf16 Ls[64 * 256];
  if (blockIdx.x >= 5120) {
    const int vb = blockIdx.x - 5120;      // 0..127
    const int b = vb >> 6, tt = vb & 63;
    const int tid = threadIdx.x;
    const __bf16* src = qkv + ((size_t)(b * 4096 + tt * 64)) * 1536 + 1280;
#pragma unroll
    for (int i = 0; i < 8; ++i)
      gl2lds16(src + (size_t)(i * 8 + (tid >> 5)) * 1536 + (tid & 31) * 8,
               &Ls[i * 2048 + tid * 8]);
    __syncthreads();
    __bf16 buf[64];
#pragma unroll
    for (int i = 0; i < 64; ++i) buf[i] = Ls[i * 256 + tid];
    __bf16* dst = vt + ((size_t)(b * 256 + tid)) * T_SEQ + tt * 64;
#pragma unroll
    for (int i = 0; i < 8; ++i)
      *(bf16x8*)&dst[i * 8] = *(const bf16x8*)&buf[i * 8];
    return;
  }

  const int inst = blockIdx.x * 4 + (threadIdx.x >> 6);
  const int lane = threadIdx.x & 63;
  const int rp = inst / 5, which = inst - rp * 5;     // rp in [0, 4096)
  const int row = rp * 2 + (lane >> 5);               // row in [0, 8192)
  const int hl = lane & 31;
  const int b = row >> 12, t = row & 4095;

  const int srcoff = (which < 4) ? which * 256 : 1024;
  const __bf16* src = qkv + (size_t)row * 1536 + srcoff;
  bf16x8 xv = *(const bf16x8*)&src[hl * 8];

  float xf[8];
  float ss = 0.f;
#pragma unroll
  for (int j = 0; j < 8; ++j) { xf[j] = (float)xv[j]; ss += xf[j] * xf[j]; }
#pragma unroll
  for (int off = 16; off >= 1; off >>= 1) ss += __shfl_xor(ss, off);
  const float rms = rsqrtf(ss * (1.0f / 256.0f) + 1e-6f);

  const float* g = (which < 4) ? qg : kg;
  const float4 gv0 = *(const float4*)&g[hl * 8];
  const float4 gv1 = *(const float4*)&g[hl * 8 + 4];
  float y[8];
  y[0] = xf[0] * rms * gv0.x; y[1] = xf[1] * rms * gv0.y;
  y[2] = xf[2] * rms * gv0.z; y[3] = xf[3] * rms * gv0.w;
  y[4] = xf[4] * rms * gv1.x; y[5] = xf[5] * rms * gv1.y;
  y[6] = xf[6] * rms * gv1.z; y[7] = xf[7] * rms * gv1.w;

  const float c_log2 = -19.931568569324174f / 128.0f;  // -log2(1e6)/128
  bf16x8 ov;
#pragma unroll
  for (int j = 0; j < 4; ++j) {
    const int p = hl * 4 + j;
    const float a = (float)t * exp2f((float)p * c_log2);
    const float sn = __sinf(a), cs = __cosf(a);
    ov[2 * j]     = (__bf16)(y[2 * j] * cs - y[2 * j + 1] * sn);
    ov[2 * j + 1] = (__bf16)(y[2 * j] * sn + y[2 * j + 1] * cs);
  }

  __bf16* dst = (which < 4)
      ? qr + ((size_t)((b * NH + which) * T_SEQ) + t) * 256
      : kr + ((size_t)(b * T_SEQ) + t) * 256;
  *(bf16x8*)&dst[hl * 8] = ov;
}

// --------------------------------------------------- flash attention, window=512
// Block = (b, h, 64-query tile), grid 512 -> 2 blocks/CU (72 KB LDS). 32-key
// tiles; K, V AND P all double-buffered, ONE barrier per tile:
//   segment jt (between barriers jt-1 and jt):
//     stage K(jt+1) [consumed post-B(jt)], stage V(jt) ... wait: V(jt) staged in
//     segment jt-1, consumed in PV(jt) post-B(jt); K staged 2 ahead.
//   loop body: QK(jt) -> softmax -> Pwrite(jt) -> BARRIER -> stage K(jt+2),
//              stage V(jt+1) -> Pread/lm/PV(jt from LDS V).
// Everything memory gets >= 1 full phase of slack; V no longer latency-exposed.
// Waves: (wq, wk): QK keys wk*16..+15 x queries wq*32..+31; PV queries
// wq*32..+31 x d-slice wk*128..+127 (K=32 -> single MFMA per (qt,n)).
// Fixed-max softmax (|score|<=16): p = exp2(s*log2e/16 - 16*log2e); l via
// ones-MFMA. Swizzles: K chunk^(row&7); V/P chunk^((row^(row>>2))&3) (2-way).
__global__ __launch_bounds__(256, 2) void attn(const __bf16* __restrict__ qr,
                                               const __bf16* __restrict__ kr,
                                               const __bf16* __restrict__ vt,
                                               __bf16* __restrict__ ao) {
  __shared__ __bf16 Ks[2][32 * 256];   // [key][d]   (2 x 16 KB)
  __shared__ __bf16 Vs[2][256 * 32];   // [d][key]   (2 x 16 KB)
  __shared__ __bf16 Ps[2][64 * 32];    // [query][key] (2 x 4 KB)

  const int bid = blockIdx.x;
  const int qi = bid & 63, h = (bid >> 6) & 3, b = bid >> 8;
  const int tid = threadIdx.x, wave = tid >> 6, lane = tid & 63;
  const int wq = wave & 1, wk = wave >> 1;
  const int lrow = lane & 15, quad = lane >> 4;
  const int l7 = lrow & 7;

  const __bf16* Q = qr + (size_t)((b * NH + h) * T_SEQ) * 256;
  const __bf16* K = kr + (size_t)(b * T_SEQ) * 256;
  const __bf16* V = vt + (size_t)(b * 256) * T_SEQ;

  const int qbase = qi * 64;

  // Q B-fragments (n=query=lane&15, k=quad*8+j) for this wave's 32 queries
  bf16x8 qf[2][8];
#pragma unroll
  for (int qt = 0; qt < 2; ++qt)
#pragma unroll
    for (int c = 0; c < 8; ++c)
      qf[qt][c] = *(const bf16x8*)&Q[(size_t)(qbase + wq * 32 + qt * 16 + lrow) * 256 +
                                     c * 32 + quad * 8];

  bf16x8 onesv;
#pragma unroll
  for (int j = 0; j < 8; ++j) onesv[j] = (__bf16)1.0f;

  floatx4 o[2][8] = {};   // [qt][n]: queries wq*32+qt*16.., d = wk*128+n*16..
  floatx4 lm[2] = {};

  const int jt0 = (qi >= 8) ? 2 * qi - 16 : 0;
  const int jt1 = 2 * qi + 1;

  // staging index precompute
  const int krow = tid >> 5;                   // K: row within 8-row round
  const int kcol = ((tid & 31) ^ (krow & 7)) * 8;
  const int vrow = tid >> 2;                   // V: d within 64-row round
  const int vcol = ((tid & 3) ^ ((vrow ^ (vrow >> 2)) & 3)) * 8;

  // prologue: stage K(jt0), K(jt0+1), V(jt0)
#pragma unroll
  for (int i = 0; i < 4; ++i)
    gl2lds16(K + (size_t)(jt0 * 32 + i * 8 + krow) * 256 + kcol,
             &Ks[jt0 & 1][i * 2048 + tid * 8]);
#pragma unroll
  for (int i = 0; i < 4; ++i)
    gl2lds16(K + (size_t)((jt0 + 1) * 32 + i * 8 + krow) * 256 + kcol,
             &Ks[(jt0 + 1) & 1][i * 2048 + tid * 8]);
#pragma unroll
  for (int i = 0; i < 4; ++i)
    gl2lds16(V + (size_t)(i * 64 + vrow) * T_SEQ + jt0 * 32 + vcol,
             &Vs[jt0 & 1][i * 2048 + tid * 8]);
  __syncthreads();

  for (int jt = jt0; jt <= jt1; ++jt) {
    const __bf16* Kb = Ks[jt & 1];

    // S^T = K Q^T for keys wk*16..+15 x queries wq*32..+31
    floatx4 s[2] = {};   // [qt]
#pragma unroll
    for (int c = 0; c < 8; ++c) {
      bf16x8 kf = *(const bf16x8*)&Kb[(wk * 16 + lrow) * 256 +
                                      ((c * 4 + quad) ^ l7) * 8];
      s[0] = mfma16(kf, qf[0][c], s[0]);
      s[1] = mfma16(kf, qf[1][c], s[1]);
    }

    const bool full = (jt <= 2 * qi - 1) && (jt >= 2 * qi - 14);

    // p = exp2(s*log2e/16 - 16*log2e); pack 4 keys -> ds_write_b64 into P
    const float C1 = 0.09016844005556021f;   // log2(e)/16
    const float C2 = 23.083120654223415f;    // 16*log2(e)
    __bf16* Pb = Ps[jt & 1];
#pragma unroll
    for (int qt = 0; qt < 2; ++qt) {
      bf16x4 pk;
#pragma unroll
      for (int r = 0; r < 4; ++r) {
        float v = s[qt][r];
        if (!full) {
          const int jk = jt * 32 + wk * 16 + quad * 4 + r;
          const int iq = qbase + wq * 32 + qt * 16 + lrow;
          v = ((jk <= iq) && (jk + 512 >= iq)) ? v : -1e30f;
        }
        pk[r] = (__bf16)exp2f(v * C1 - C2);
      }
      const int q = wq * 32 + qt * 16 + lrow;
      const int chunk = (wk * 2 + (quad >> 1)) ^ ((q ^ (q >> 2)) & 3);
      *(bf16x4*)((char*)Pb + q * 64 + chunk * 16 + (quad & 1) * 8) = pk;
    }
    __syncthreads();   // the ONE barrier: P(jt)/K(jt+1) visible; reads done

    if (jt + 2 <= jt1) {   // stage K(jt+2) into the buffer QK(jt) just vacated
#pragma unroll
      for (int i = 0; i < 4; ++i)
        gl2lds16(K + (size_t)((jt + 2) * 32 + i * 8 + krow) * 256 + kcol,
                 &Ks[jt & 1][i * 2048 + tid * 8]);
    }
    if (jt + 1 <= jt1) {   // stage V(jt+1), consumed after the NEXT barrier
#pragma unroll
      for (int i = 0; i < 4; ++i)
        gl2lds16(V + (size_t)(i * 64 + vrow) * T_SEQ + (jt + 1) * 32 + vcol,
                 &Vs[(jt + 1) & 1][i * 2048 + tid * 8]);
    }

    // P A-fragments (m=query=lane&15, k=key=quad*8+j; K=32 exactly)
    bf16x8 pf[2];
#pragma unroll
    for (int qt = 0; qt < 2; ++qt) {
      const int q = wq * 32 + qt * 16 + lrow;
      pf[qt] = *(const bf16x8*)((char*)Pb + q * 64 +
                                (quad ^ ((q ^ (q >> 2)) & 3)) * 16);
    }

    // row-sums via ones-MFMA
    lm[0] = mfma16(pf[0], onesv, lm[0]);
    lm[1] = mfma16(pf[1], onesv, lm[1]);

    // O += P V over this wave's d-slice; V from LDS (staged last segment)
    const __bf16* Vb = Vs[jt & 1];
#pragma unroll
    for (int n = 0; n < 8; ++n) {
      const int row = wk * 128 + n * 16 + lrow;
      bf16x8 vf = *(const bf16x8*)&Vb[row * 32 +
                                      ((quad ^ ((row ^ (row >> 2)) & 3)) * 8)];
      o[0][n] = mfma16(pf[0], vf, o[0][n]);
      o[1][n] = mfma16(pf[1], vf, o[1][n]);
    }
  }

  // epilogue: O/l -> ao in (B,T,H*hd) layout (A matrix of the out-projection)
#pragma unroll
  for (int qt = 0; qt < 2; ++qt)
#pragma unroll
    for (int r = 0; r < 4; ++r) {
      const float rl = 1.0f / lm[qt][r];
      const int tg = qbase + wq * 32 + qt * 16 + quad * 4 + r;
#pragma unroll
      for (int n = 0; n < 8; ++n)
        ao[((size_t)(b * T_SEQ + tg)) * CDIM + h * 256 + wk * 128 + n * 16 + lrow] =
            (__bf16)(o[qt][n][r] * rl);
    }
}

// -----------------------------------------------------------------------------
extern "C" void kernel_launch(void* const* d_in, const int* in_sizes, int n_in,
                              void* d_out, int out_size, void* d_ws, size_t ws_size,
                              hipStream_t stream) {
  const float* x  = (const float*)d_in[0];
  const float* Wq = (const float*)d_in[1];
  const float* Wk = (const float*)d_in[2];
  const float* Wv = (const float*)d_in[3];
  const float* Wo = (const float*)d_in[4];
  const float* qg = (const float*)d_in[5];
  const float* kg = (const float*)d_in[6];
  float* out = (float*)d_out;

  const size_t M = (size_t)NB * T_SEQ;  // 8192
  char* ws = (char*)d_ws;
  __bf16* xb  = (__bf16*)ws; ws += M * CDIM * 2;
  __bf16* wb  = (__bf16*)ws; ws += (size_t)1536 * CDIM * 2;
  __bf16* wob = (__bf16*)ws; ws += (size_t)CDIM * CDIM * 2;
  __bf16* qkv = (__bf16*)ws; ws += M * 1536 * 2;
  __bf16* qr  = (__bf16*)ws; ws += M * CDIM * 2;
  __bf16* kr  = (__bf16*)ws; ws += M * HD * 2;
  __bf16* vt  = (__bf16*)ws; ws += M * HD * 2;
  __bf16* ao  = (__bf16*)ws;

  // all fp32->bf16 conversions in one launch
  cvt_all<<<10752, 256, 0, stream>>>(x, Wq, Wk, Wv, Wo, xb, wb, wob);

  // QKV projection: (8192 x 1536) = xb @ [Wq;Wk;Wv]^T
  gemm_bt<__bf16><<<dim3(12, 64), 256, 0, stream>>>(xb, wb, qkv, 8192, 1536, 1024);

  // per-head RMSNorm + RoPE on Q,K; V transpose via LDS tiles
  rmsrope<<<5248, 256, 0, stream>>>(qkv, qg, kg, qr, kr, vt);

  // sliding-window flash attention: 64-query blocks, 32-key tiles, all staged
  attn<<<NB * NH * (T_SEQ / 64), 256, 0, stream>>>(qr, kr, vt, ao);

  // output projection to fp32 d_out
  gemm_bt<float><<<dim3(8, 64), 256, 0, stream>>>(ao, wob, out, 8192, 1024, 1024);
}

// Round 8
// 207.001 us; speedup vs baseline: 1.1926x; 1.1926x over previous
//
#include <hip/hip_runtime.h>
#include <cstdint>
#include <cstddef>

// B=2, T=4096, C=1024, H=4, G=1, hd=256, window=512, rope base 1e6, eps 1e-6.
#define T_SEQ 4096
#define NB    2
#define CDIM  1024
#define HD    256
#define NH    4

typedef __attribute__((ext_vector_type(8))) __bf16 bf16x8;
typedef __attribute__((ext_vector_type(4))) __bf16 bf16x4;
typedef __attribute__((ext_vector_type(4))) float  floatx4;

__device__ __forceinline__ floatx4 mfma16(bf16x8 a, bf16x8 b, floatx4 c) {
  return __builtin_amdgcn_mfma_f32_16x16x32_bf16(a, b, c, 0, 0, 0);
}

// async global->LDS, 16B/lane. LDS dest is wave-uniform base + lane*16 (no
// scatter) -- bank-deconflict swizzles are applied to the GLOBAL source
// address (XOR of the 16B-chunk index, stays inside one row's span).
// NOTE (R7 lesson): do NOT replace LDS staging with direct per-fragment global
// loads -- fragment layouts are row-gathers (16 rows x 16B), uncoalesced, 4x
// HBM over-fetch. glds keeps the global side coalesced; LDS does the reshape.
__device__ __forceinline__ void gl2lds16(const void* g, void* l) {
  __builtin_amdgcn_global_load_lds(
      (__attribute__((address_space(1))) void*)g,
      (__attribute__((address_space(3))) void*)l, 16, 0, 0);
}

// ------------------------------------------- fp32 -> bf16, all 5 inputs fused
__global__ __launch_bounds__(256) void cvt_all(const float* __restrict__ x,
                                               const float* __restrict__ wq,
                                               const float* __restrict__ wk,
                                               const float* __restrict__ wv,
                                               const float* __restrict__ wo,
                                               __bf16* __restrict__ xb,
                                               __bf16* __restrict__ wb,
                                               __bf16* __restrict__ wob) {
  int i = blockIdx.x * 256 + threadIdx.x;   // float4 index, [0, 2752512)
  const float* src;
  __bf16* dst;
  int off;
  if (i < 2097152)      { src = x;  dst = xb;            off = i; }
  else if (i < 2359296) { src = wq; dst = wb;            off = i - 2097152; }
  else if (i < 2424832) { src = wk; dst = wb + 1048576;  off = i - 2359296; }
  else if (i < 2490368) { src = wv; dst = wb + 1310720;  off = i - 2424832; }
  else                  { src = wo; dst = wob;           off = i - 2490368; }
  float4 v = ((const float4*)src)[off];
  bf16x4 o;
  o[0] = (__bf16)v.x; o[1] = (__bf16)v.y; o[2] = (__bf16)v.z; o[3] = (__bf16)v.w;
  *(bf16x4*)&dst[(size_t)off * 4] = o;
}

// ------------------------------------------------- C(M,N) = A(M,K) @ B(N,K)^T
// m97 structure + XOR-swizzled LDS (R6-proven). Both A and B staged via
// global_load_lds (coalesced), 128x128 tile, BK=64, 2 barriers/iter,
// 32 KB LDS -> 3 blocks/CU. M,N multiples of 128; K multiple of 64.
template <typename OutT>
__global__ __launch_bounds__(256) void gemm_bt(const __bf16* __restrict__ A,
                                               const __bf16* __restrict__ B,
                                               OutT* __restrict__ C,
                                               int M, int N, int K) {
  __shared__ __bf16 As[128 * 64];
  __shared__ __bf16 Bs[128 * 64];
  const int tid  = threadIdx.x;
  const int lane = tid & 63;
  const int wave = tid >> 6;
  const int wm = wave >> 1, wn = wave & 1;
  const int lrow = lane & 15, quad = lane >> 4;
  const int bm = blockIdx.y, bn = blockIdx.x;

  const __bf16* gA = A + (size_t)(bm * 128) * K;
  const __bf16* gB = B + (size_t)(bn * 128) * K;
  const int arow = tid >> 3;
  const int acol = ((tid & 7) ^ ((tid >> 3) & 7)) * 8;
  const int l7 = lrow & 7;

  floatx4 acc[4][4] = {};

  for (int kt = 0; kt < K; kt += 64) {
#pragma unroll
    for (int i = 0; i < 4; ++i)
      gl2lds16(gA + (size_t)(i * 32 + arow) * K + kt + acol, &As[i * 2048 + tid * 8]);
#pragma unroll
    for (int i = 0; i < 4; ++i)
      gl2lds16(gB + (size_t)(i * 32 + arow) * K + kt + acol, &Bs[i * 2048 + tid * 8]);
    __syncthreads();
#pragma unroll
    for (int kk = 0; kk < 2; ++kk) {
      bf16x8 af[4], bfr[4];
#pragma unroll
      for (int mi = 0; mi < 4; ++mi)
        af[mi] = *(const bf16x8*)&As[(wm * 64 + mi * 16 + lrow) * 64 +
                                     ((kk * 4 + quad) ^ l7) * 8];
#pragma unroll
      for (int ni = 0; ni < 4; ++ni)
        bfr[ni] = *(const bf16x8*)&Bs[(wn * 64 + ni * 16 + lrow) * 64 +
                                      ((kk * 4 + quad) ^ l7) * 8];
#pragma unroll
      for (int mi = 0; mi < 4; ++mi)
#pragma unroll
        for (int ni = 0; ni < 4; ++ni)
          acc[mi][ni] = mfma16(af[mi], bfr[ni], acc[mi][ni]);
    }
    __syncthreads();
  }

  const int row0 = bm * 128 + wm * 64;
  const int col0 = bn * 128 + wn * 64;
#pragma unroll
  for (int mi = 0; mi < 4; ++mi)
#pragma unroll
    for (int ni = 0; ni < 4; ++ni)
#pragma unroll
      for (int r = 0; r < 4; ++r) {
        int row = row0 + mi * 16 + quad * 4 + r;   // C/D: row = quad*4 + reg
        int col = col0 + ni * 16 + lrow;           //      col = lane&15
        C[(size_t)row * N + col] = (OutT)acc[mi][ni][r];
      }
}

// ------------------------------------------------ RMSNorm + RoPE (+ V transpose)
__global__ __launch_bounds__(256) void rmsrope(const __bf16* __restrict__ qkv,
                                               const float* __restrict__ qg,
                                               const float* __restrict__ kg,
                                               __bf16* __restrict__ qr,
                                               __bf16* __restrict__ kr,
                                               __bf16* __restrict__ vt) {
  __shared__ __bf16 Ls[64 * 256];
  if (blockIdx.x >= 5120) {
    const int vb = blockIdx.x - 5120;      // 0..127
    const int b = vb >> 6, tt = vb & 63;
    const int tid = threadIdx.x;
    const __bf16* src = qkv + ((size_t)(b * 4096 + tt * 64)) * 1536 + 1280;
#pragma unroll
    for (int i = 0; i < 8; ++i)
      gl2lds16(src + (size_t)(i * 8 + (tid >> 5)) * 1536 + (tid & 31) * 8,
               &Ls[i * 2048 + tid * 8]);
    __syncthreads();
    __bf16 buf[64];
#pragma unroll
    for (int i = 0; i < 64; ++i) buf[i] = Ls[i * 256 + tid];
    __bf16* dst = vt + ((size_t)(b * 256 + tid)) * T_SEQ + tt * 64;
#pragma unroll
    for (int i = 0; i < 8; ++i)
      *(bf16x8*)&dst[i * 8] = *(const bf16x8*)&buf[i * 8];
    return;
  }

  const int inst = blockIdx.x * 4 + (threadIdx.x >> 6);
  const int lane = threadIdx.x & 63;
  const int rp = inst / 5, which = inst - rp * 5;     // rp in [0, 4096)
  const int row = rp * 2 + (lane >> 5);               // row in [0, 8192)
  const int hl = lane & 31;
  const int b = row >> 12, t = row & 4095;

  const int srcoff = (which < 4) ? which * 256 : 1024;
  const __bf16* src = qkv + (size_t)row * 1536 + srcoff;
  bf16x8 xv = *(const bf16x8*)&src[hl * 8];

  float xf[8];
  float ss = 0.f;
#pragma unroll
  for (int j = 0; j < 8; ++j) { xf[j] = (float)xv[j]; ss += xf[j] * xf[j]; }
#pragma unroll
  for (int off = 16; off >= 1; off >>= 1) ss += __shfl_xor(ss, off);
  const float rms = rsqrtf(ss * (1.0f / 256.0f) + 1e-6f);

  const float* g = (which < 4) ? qg : kg;
  const float4 gv0 = *(const float4*)&g[hl * 8];
  const float4 gv1 = *(const float4*)&g[hl * 8 + 4];
  float y[8];
  y[0] = xf[0] * rms * gv0.x; y[1] = xf[1] * rms * gv0.y;
  y[2] = xf[2] * rms * gv0.z; y[3] = xf[3] * rms * gv0.w;
  y[4] = xf[4] * rms * gv1.x; y[5] = xf[5] * rms * gv1.y;
  y[6] = xf[6] * rms * gv1.z; y[7] = xf[7] * rms * gv1.w;

  const float c_log2 = -19.931568569324174f / 128.0f;  // -log2(1e6)/128
  bf16x8 ov;
#pragma unroll
  for (int j = 0; j < 4; ++j) {
    const int p = hl * 4 + j;
    const float a = (float)t * exp2f((float)p * c_log2);
    const float sn = __sinf(a), cs = __cosf(a);
    ov[2 * j]     = (__bf16)(y[2 * j] * cs - y[2 * j + 1] * sn);
    ov[2 * j + 1] = (__bf16)(y[2 * j] * sn + y[2 * j + 1] * cs);
  }

  __bf16* dst = (which < 4)
      ? qr + ((size_t)((b * NH + which) * T_SEQ) + t) * 256
      : kr + ((size_t)(b * T_SEQ) + t) * 256;
  *(bf16x8*)&dst[hl * 8] = ov;
}

// --------------------------------------------------- flash attention, window=512
// (R7 structure, kept.) Block = (b, h, 64-query tile), grid 512 -> 2 blocks/CU
// (72 KB LDS). 32-key tiles; K, V and P all double-buffered, ONE barrier/tile;
// K staged 2 tiles ahead, V 1 ahead, all consumed from LDS. Waves (wq,wk):
// QK keys wk*16..+15 x queries wq*32..+31; PV queries wq*32..+31 x d-slice
// wk*128..+127. Fixed-max softmax (|score|<=16): p = exp2(s*log2e/16-16*log2e);
// l via ones-MFMA. Swizzles: K chunk^(row&7); V/P chunk^((row^(row>>2))&3).
__global__ __launch_bounds__(256, 2) void attn(const __bf16* __restrict__ qr,
                                               const __bf16* __restrict__ kr,
                                               const __bf16* __restrict__ vt,
                                               __bf16* __restrict__ ao) {
  __shared__ __bf16 Ks[2][32 * 256];   // [key][d]   (2 x 16 KB)
  __shared__ __bf16 Vs[2][256 * 32];   // [d][key]   (2 x 16 KB)
  __shared__ __bf16 Ps[2][64 * 32];    // [query][key] (2 x 4 KB)

  const int bid = blockIdx.x;
  const int qi = bid & 63, h = (bid >> 6) & 3, b = bid >> 8;
  const int tid = threadIdx.x, wave = tid >> 6, lane = tid & 63;
  const int wq = wave & 1, wk = wave >> 1;
  const int lrow = lane & 15, quad = lane >> 4;
  const int l7 = lrow & 7;

  const __bf16* Q = qr + (size_t)((b * NH + h) * T_SEQ) * 256;
  const __bf16* K = kr + (size_t)(b * T_SEQ) * 256;
  const __bf16* V = vt + (size_t)(b * 256) * T_SEQ;

  const int qbase = qi * 64;

  bf16x8 qf[2][8];
#pragma unroll
  for (int qt = 0; qt < 2; ++qt)
#pragma unroll
    for (int c = 0; c < 8; ++c)
      qf[qt][c] = *(const bf16x8*)&Q[(size_t)(qbase + wq * 32 + qt * 16 + lrow) * 256 +
                                     c * 32 + quad * 8];

  bf16x8 onesv;
#pragma unroll
  for (int j = 0; j < 8; ++j) onesv[j] = (__bf16)1.0f;

  floatx4 o[2][8] = {};
  floatx4 lm[2] = {};

  const int jt0 = (qi >= 8) ? 2 * qi - 16 : 0;
  const int jt1 = 2 * qi + 1;

  const int krow = tid >> 5;
  const int kcol = ((tid & 31) ^ (krow & 7)) * 8;
  const int vrow = tid >> 2;
  const int vcol = ((tid & 3) ^ ((vrow ^ (vrow >> 2)) & 3)) * 8;

  // prologue: stage K(jt0), K(jt0+1), V(jt0)
#pragma unroll
  for (int i = 0; i < 4; ++i)
    gl2lds16(K + (size_t)(jt0 * 32 + i * 8 + krow) * 256 + kcol,
             &Ks[jt0 & 1][i * 2048 + tid * 8]);
#pragma unroll
  for (int i = 0; i < 4; ++i)
    gl2lds16(K + (size_t)((jt0 + 1) * 32 + i * 8 + krow) * 256 + kcol,
             &Ks[(jt0 + 1) & 1][i * 2048 + tid * 8]);
#pragma unroll
  for (int i = 0; i < 4; ++i)
    gl2lds16(V + (size_t)(i * 64 + vrow) * T_SEQ + jt0 * 32 + vcol,
             &Vs[jt0 & 1][i * 2048 + tid * 8]);
  __syncthreads();

  for (int jt = jt0; jt <= jt1; ++jt) {
    const __bf16* Kb = Ks[jt & 1];

    floatx4 s[2] = {};
#pragma unroll
    for (int c = 0; c < 8; ++c) {
      bf16x8 kf = *(const bf16x8*)&Kb[(wk * 16 + lrow) * 256 +
                                      ((c * 4 + quad) ^ l7) * 8];
      s[0] = mfma16(kf, qf[0][c], s[0]);
      s[1] = mfma16(kf, qf[1][c], s[1]);
    }

    const bool full = (jt <= 2 * qi - 1) && (jt >= 2 * qi - 14);

    const float C1 = 0.09016844005556021f;   // log2(e)/16
    const float C2 = 23.083120654223415f;    // 16*log2(e)
    __bf16* Pb = Ps[jt & 1];
#pragma unroll
    for (int qt = 0; qt < 2; ++qt) {
      bf16x4 pk;
#pragma unroll
      for (int r = 0; r < 4; ++r) {
        float v = s[qt][r];
        if (!full) {
          const int jk = jt * 32 + wk * 16 + quad * 4 + r;
          const int iq = qbase + wq * 32 + qt * 16 + lrow;
          v = ((jk <= iq) && (jk + 512 >= iq)) ? v : -1e30f;
        }
        pk[r] = (__bf16)exp2f(v * C1 - C2);
      }
      const int q = wq * 32 + qt * 16 + lrow;
      const int chunk = (wk * 2 + (quad >> 1)) ^ ((q ^ (q >> 2)) & 3);
      *(bf16x4*)((char*)Pb + q * 64 + chunk * 16 + (quad & 1) * 8) = pk;
    }
    __syncthreads();   // the ONE barrier

    if (jt + 2 <= jt1) {
#pragma unroll
      for (int i = 0; i < 4; ++i)
        gl2lds16(K + (size_t)((jt + 2) * 32 + i * 8 + krow) * 256 + kcol,
                 &Ks[jt & 1][i * 2048 + tid * 8]);
    }
    if (jt + 1 <= jt1) {
#pragma unroll
      for (int i = 0; i < 4; ++i)
        gl2lds16(V + (size_t)(i * 64 + vrow) * T_SEQ + (jt + 1) * 32 + vcol,
                 &Vs[(jt + 1) & 1][i * 2048 + tid * 8]);
    }

    bf16x8 pf[2];
#pragma unroll
    for (int qt = 0; qt < 2; ++qt) {
      const int q = wq * 32 + qt * 16 + lrow;
      pf[qt] = *(const bf16x8*)((char*)Pb + q * 64 +
                                (quad ^ ((q ^ (q >> 2)) & 3)) * 16);
    }

    lm[0] = mfma16(pf[0], onesv, lm[0]);
    lm[1] = mfma16(pf[1], onesv, lm[1]);

    const __bf16* Vb = Vs[jt & 1];
#pragma unroll
    for (int n = 0; n < 8; ++n) {
      const int row = wk * 128 + n * 16 + lrow;
      bf16x8 vf = *(const bf16x8*)&Vb[row * 32 +
                                      ((quad ^ ((row ^ (row >> 2)) & 3)) * 8)];
      o[0][n] = mfma16(pf[0], vf, o[0][n]);
      o[1][n] = mfma16(pf[1], vf, o[1][n]);
    }
  }

  // epilogue: O/l -> ao in (B,T,H*hd) layout (A matrix of the out-projection)
#pragma unroll
  for (int qt = 0; qt < 2; ++qt)
#pragma unroll
    for (int r = 0; r < 4; ++r) {
      const float rl = 1.0f / lm[qt][r];
      const int tg = qbase + wq * 32 + qt * 16 + quad * 4 + r;
#pragma unroll
      for (int n = 0; n < 8; ++n)
        ao[((size_t)(b * T_SEQ + tg)) * CDIM + h * 256 + wk * 128 + n * 16 + lrow] =
            (__bf16)(o[qt][n][r] * rl);
    }
}

// -----------------------------------------------------------------------------
extern "C" void kernel_launch(void* const* d_in, const int* in_sizes, int n_in,
                              void* d_out, int out_size, void* d_ws, size_t ws_size,
                              hipStream_t stream) {
  const float* x  = (const float*)d_in[0];
  const float* Wq = (const float*)d_in[1];
  const float* Wk = (const float*)d_in[2];
  const float* Wv = (const float*)d_in[3];
  const float* Wo = (const float*)d_in[4];
  const float* qg = (const float*)d_in[5];
  const float* kg = (const float*)d_in[6];
  float* out = (float*)d_out;

  const size_t M = (size_t)NB * T_SEQ;  // 8192
  char* ws = (char*)d_ws;
  __bf16* xb  = (__bf16*)ws; ws += M * CDIM * 2;
  __bf16* wb  = (__bf16*)ws; ws += (size_t)1536 * CDIM * 2;
  __bf16* wob = (__bf16*)ws; ws += (size_t)CDIM * CDIM * 2;
  __bf16* qkv = (__bf16*)ws; ws += M * 1536 * 2;
  __bf16* qr  = (__bf16*)ws; ws += M * CDIM * 2;
  __bf16* kr  = (__bf16*)ws; ws += M * HD * 2;
  __bf16* vt  = (__bf16*)ws; ws += M * HD * 2;
  __bf16* ao  = (__bf16*)ws;

  // all fp32->bf16 conversions in one launch
  cvt_all<<<10752, 256, 0, stream>>>(x, Wq, Wk, Wv, Wo, xb, wb, wob);

  // QKV projection: (8192 x 1536) = xb @ [Wq;Wk;Wv]^T
  gemm_bt<__bf16><<<dim3(12, 64), 256, 0, stream>>>(xb, wb, qkv, 8192, 1536, 1024);

  // per-head RMSNorm + RoPE on Q,K; V transpose via LDS tiles
  rmsrope<<<5248, 256, 0, stream>>>(qkv, qg, kg, qr, kr, vt);

  // sliding-window flash attention: 64-query blocks, 32-key tiles, all staged
  attn<<<NB * NH * (T_SEQ / 64), 256, 0, stream>>>(qr, kr, vt, ao);

  // output projection to fp32 d_out
  gemm_bt<float><<<dim3(8, 64), 256, 0, stream>>>(ao, wob, out, 8192, 1024, 1024);
}